// Round 3
// baseline (976.187 us; speedup 1.0000x reference)
//
#include <hip/hip_runtime.h>
#include <math.h>

// Swin block: B=8, C=256, H=W=128, WS=8, SS=4, NH=8, dh=32
// Pipeline: wconv -> ln1(h to d_out) -> attn(h->o) -> mlp(o->out)

#define LDH 264   // bf16 row stride for [64][256] LDS tiles (528B rows, 16B-aligned)

typedef __attribute__((ext_vector_type(8))) short bf16x8;
typedef __attribute__((ext_vector_type(4))) float f32x4;

static __device__ __forceinline__ float bf2f(short s){
  union { unsigned u; float f; } cv;
  cv.u = ((unsigned)(unsigned short)s) << 16;
  return cv.f;
}
static __device__ __forceinline__ short f2bf(float f){
  union { float f; unsigned u; } cv; cv.f = f;
  unsigned r = (cv.u + 0x7FFFu + ((cv.u >> 16) & 1u)) >> 16;  // RNE
  return (short)r;
}
static __device__ __forceinline__ float gelu_f(float x){
  return 0.5f * x * (1.0f + erff(x * 0.7071067811865475f));
}

// ---------------- K0: merged fp32 -> bf16 weight convert ----------------
// ws layout (shorts): [0,196608) wqkv | [196608,262144) wout | [262144,524288) w1 | [524288,786432) w2
__global__ void wconv_kernel(const float* __restrict__ inw, const float* __restrict__ outw,
                             const float* __restrict__ w1f, const float* __restrict__ w2f,
                             short* __restrict__ dst){
  int i = blockIdx.x * 256 + threadIdx.x;   // grid covers exactly 786432
  const float* s; int off;
  if (i < 196608){ s = inw;  off = 0; }
  else if (i < 262144){ s = outw; off = 196608; }
  else if (i < 524288){ s = w1f;  off = 262144; }
  else { s = w2f; off = 524288; }
  dst[i] = f2bf(s[i - off]);
}

// ---------------- K1a: LN1 -> h (bf16, window-token-major, lives in d_out) ----------------
__global__ __launch_bounds__(256, 4)
void ln1_kernel(const float* __restrict__ x, const float* __restrict__ ln1w,
                const float* __restrict__ ln1b, short* __restrict__ h_g){
  __shared__ float red_s[256], red_q2[256];
  const int tid = threadIdx.x, wv = tid >> 6, ln = tid & 63;
  const int wi = blockIdx.x;
  const int b = wi >> 8, wh = (wi >> 4) & 15, ww = wi & 15;
  const int hh = (wh*8 + (ln >> 3) + 4) & 127;   // roll(-4)
  const int wc = (ww*8 + (ln & 7) + 4) & 127;
  const int offhw = hh*128 + wc;
  const int xbase = b << 22;
  const int cbeg = wv * 64;
  float vals[64], s = 0.f, sq = 0.f;
  #pragma unroll
  for (int j = 0; j < 64; ++j){
    float v = x[xbase + ((cbeg + j) << 14) + offhw];
    vals[j] = v; s += v; sq += v*v;
  }
  red_s[wv*64 + ln] = s; red_q2[wv*64 + ln] = sq;
  __syncthreads();
  float sum = red_s[ln] + red_s[64+ln] + red_s[128+ln] + red_s[192+ln];
  float ssq = red_q2[ln] + red_q2[64+ln] + red_q2[128+ln] + red_q2[192+ln];
  float mean = sum * 0.00390625f;
  float var  = ssq * 0.00390625f - mean*mean;
  float rstd = rsqrtf(var + 1e-5f);
  #pragma unroll
  for (int q = 0; q < 8; ++q){
    bf16x8 pk;
    #pragma unroll
    for (int e = 0; e < 8; ++e){
      const int c = cbeg + q*8 + e;
      pk[e] = f2bf((vals[q*8+e] - mean) * rstd * ln1w[c] + ln1b[c]);
    }
    *(bf16x8*)&h_g[(wi*64 + ln)*256 + cbeg + q*8] = pk;
  }
}

// ---------------- K1b: per-window attention (q/k/v GEMMs stream h from global) ----------------
// LDS: 4 waves x (slotA [64][40] q->P, slotB [64][40] k -> vT[32][72]) = 40960 B, no barriers.
__global__ __launch_bounds__(256, 4)
void attn_kernel(const short* __restrict__ h_g, const float* __restrict__ inb,
                 const short* __restrict__ wqkv, short* __restrict__ o_g){
  __shared__ short slots[20480];
  const int tid = threadIdx.x, wv = tid >> 6, ln = tid & 63;
  const int rowa = ln & 15, kg = ln >> 4;
  short* slotA = slots + wv*5120;
  short* slotB = slotA + 2560;
  const int wi64 = blockIdx.x * 64;
  const float scale = 0.1767766952966369f;  // 1/sqrt(32)

  #pragma unroll
  for (int hd = 0; hd < 2; ++hd){
    const int hc = (2*wv + hd) * 32;

    // ---- q -> slotA ----
    {
      f32x4 acc[4][2];
      #pragma unroll
      for (int mt=0;mt<4;++mt){ acc[mt][0]=(f32x4){0,0,0,0}; acc[mt][1]=(f32x4){0,0,0,0}; }
      #pragma unroll
      for (int kt=0;kt<8;++kt){
        bf16x8 a[4], bw[2];
        #pragma unroll
        for (int mt=0;mt<4;++mt)
          a[mt] = *(const bf16x8*)&h_g[(wi64 + mt*16+rowa)*256 + kt*32 + kg*8];
        #pragma unroll
        for (int nt=0;nt<2;++nt)
          bw[nt] = *(const bf16x8*)&wqkv[(hc + nt*16+rowa)*256 + kt*32 + kg*8];
        #pragma unroll
        for (int mt=0;mt<4;++mt)
          #pragma unroll
          for (int nt=0;nt<2;++nt)
            acc[mt][nt] = __builtin_amdgcn_mfma_f32_16x16x32_bf16(a[mt], bw[nt], acc[mt][nt], 0, 0, 0);
      }
      #pragma unroll
      for (int nt=0;nt<2;++nt){
        const float bias = inb[hc + nt*16 + rowa];
        #pragma unroll
        for (int mt=0;mt<4;++mt)
          #pragma unroll
          for (int i=0;i<4;++i)
            slotA[(mt*16 + kg*4 + i)*40 + nt*16 + rowa] = f2bf(acc[mt][nt][i] + bias);
      }
    }
    // ---- k -> slotB ----
    {
      f32x4 acc[4][2];
      #pragma unroll
      for (int mt=0;mt<4;++mt){ acc[mt][0]=(f32x4){0,0,0,0}; acc[mt][1]=(f32x4){0,0,0,0}; }
      #pragma unroll
      for (int kt=0;kt<8;++kt){
        bf16x8 a[4], bw[2];
        #pragma unroll
        for (int mt=0;mt<4;++mt)
          a[mt] = *(const bf16x8*)&h_g[(wi64 + mt*16+rowa)*256 + kt*32 + kg*8];
        #pragma unroll
        for (int nt=0;nt<2;++nt)
          bw[nt] = *(const bf16x8*)&wqkv[(256 + hc + nt*16+rowa)*256 + kt*32 + kg*8];
        #pragma unroll
        for (int mt=0;mt<4;++mt)
          #pragma unroll
          for (int nt=0;nt<2;++nt)
            acc[mt][nt] = __builtin_amdgcn_mfma_f32_16x16x32_bf16(a[mt], bw[nt], acc[mt][nt], 0, 0, 0);
      }
      #pragma unroll
      for (int nt=0;nt<2;++nt){
        const float bias = inb[256 + hc + nt*16 + rowa];
        #pragma unroll
        for (int mt=0;mt<4;++mt)
          #pragma unroll
          for (int i=0;i<4;++i)
            slotB[(mt*16 + kg*4 + i)*40 + nt*16 + rowa] = f2bf(acc[mt][nt][i] + bias);
      }
    }

    // ---- S = q @ k^T ----
    f32x4 sacc[4][4];
    #pragma unroll
    for (int mt=0;mt<4;++mt)
      #pragma unroll
      for (int nt=0;nt<4;++nt)
        sacc[mt][nt] = (f32x4){0.f,0.f,0.f,0.f};
    {
      bf16x8 aq[4], bk[4];
      #pragma unroll
      for (int mt=0;mt<4;++mt)
        aq[mt] = *(const bf16x8*)&slotA[(mt*16+rowa)*40 + kg*8];
      #pragma unroll
      for (int nt=0;nt<4;++nt)
        bk[nt] = *(const bf16x8*)&slotB[(nt*16+rowa)*40 + kg*8];
      #pragma unroll
      for (int mt=0;mt<4;++mt)
        #pragma unroll
        for (int nt=0;nt<4;++nt)
          sacc[mt][nt] = __builtin_amdgcn_mfma_f32_16x16x32_bf16(aq[mt], bk[nt], sacc[mt][nt], 0, 0, 0);
    }

    // ---- softmax (row = query = mt*16+kg*4+i; 16 rowa-lanes x 4 nt-tiles = 64 kv) ----
    #pragma unroll
    for (int mt=0;mt<4;++mt){
      #pragma unroll
      for (int i=0;i<4;++i){
        float v0 = sacc[mt][0][i]*scale;
        float v1 = sacc[mt][1][i]*scale;
        float v2 = sacc[mt][2][i]*scale;
        float v3 = sacc[mt][3][i]*scale;
        float mx = fmaxf(fmaxf(v0,v1), fmaxf(v2,v3));
        #pragma unroll
        for (int d=1; d<16; d<<=1) mx = fmaxf(mx, __shfl_xor(mx, d, 64));
        v0 = __expf(v0-mx); v1 = __expf(v1-mx); v2 = __expf(v2-mx); v3 = __expf(v3-mx);
        float sm = v0+v1+v2+v3;
        #pragma unroll
        for (int d=1; d<16; d<<=1) sm += __shfl_xor(sm, d, 64);
        const float inv = 1.f / sm;
        sacc[mt][0][i] = v0*inv; sacc[mt][1][i] = v1*inv;
        sacc[mt][2][i] = v2*inv; sacc[mt][3][i] = v3*inv;
      }
    }

    // ---- P chunk 0 -> slotA (frees sacc[..][0,1]) ----
    #pragma unroll
    for (int ntl=0; ntl<2; ++ntl)
      #pragma unroll
      for (int mt=0;mt<4;++mt)
        #pragma unroll
        for (int i=0;i<4;++i)
          slotA[(mt*16 + kg*4 + i)*40 + ntl*16 + rowa] = f2bf(sacc[mt][ntl][i]);

    // ---- v -> vT [32][72] in slotB (k consumed by S already; same-wave DS order) ----
    {
      f32x4 acc[4][2];
      #pragma unroll
      for (int mt=0;mt<4;++mt){ acc[mt][0]=(f32x4){0,0,0,0}; acc[mt][1]=(f32x4){0,0,0,0}; }
      #pragma unroll
      for (int kt=0;kt<8;++kt){
        bf16x8 a[4], bw[2];
        #pragma unroll
        for (int mt=0;mt<4;++mt)
          a[mt] = *(const bf16x8*)&h_g[(wi64 + mt*16+rowa)*256 + kt*32 + kg*8];
        #pragma unroll
        for (int nt=0;nt<2;++nt)
          bw[nt] = *(const bf16x8*)&wqkv[(512 + hc + nt*16+rowa)*256 + kt*32 + kg*8];
        #pragma unroll
        for (int mt=0;mt<4;++mt)
          #pragma unroll
          for (int nt=0;nt<2;++nt)
            acc[mt][nt] = __builtin_amdgcn_mfma_f32_16x16x32_bf16(a[mt], bw[nt], acc[mt][nt], 0, 0, 0);
      }
      #pragma unroll
      for (int nt=0;nt<2;++nt){
        const float bias = inb[512 + hc + nt*16 + rowa];
        #pragma unroll
        for (int mt=0;mt<4;++mt)
          #pragma unroll
          for (int i=0;i<4;++i)
            slotB[(nt*16 + rowa)*72 + mt*16 + kg*4 + i] = f2bf(acc[mt][nt][i] + bias);  // [ch][tok]
      }
    }

    // ---- PV: chunk 0, then write P chunk 1, then chunk 1 ----
    f32x4 oacc[4][2];
    #pragma unroll
    for (int mt=0;mt<4;++mt){ oacc[mt][0]=(f32x4){0,0,0,0}; oacc[mt][1]=(f32x4){0,0,0,0}; }
    {
      bf16x8 ap[4], bv[2];
      #pragma unroll
      for (int mt=0;mt<4;++mt)
        ap[mt] = *(const bf16x8*)&slotA[(mt*16+rowa)*40 + kg*8];
      #pragma unroll
      for (int nt=0;nt<2;++nt)
        bv[nt] = *(const bf16x8*)&slotB[(nt*16+rowa)*72 + kg*8];
      #pragma unroll
      for (int mt=0;mt<4;++mt)
        #pragma unroll
        for (int nt=0;nt<2;++nt)
          oacc[mt][nt] = __builtin_amdgcn_mfma_f32_16x16x32_bf16(ap[mt], bv[nt], oacc[mt][nt], 0, 0, 0);
    }
    #pragma unroll
    for (int ntl=0; ntl<2; ++ntl)
      #pragma unroll
      for (int mt=0;mt<4;++mt)
        #pragma unroll
        for (int i=0;i<4;++i)
          slotA[(mt*16 + kg*4 + i)*40 + ntl*16 + rowa] = f2bf(sacc[mt][2+ntl][i]);
    {
      bf16x8 ap[4], bv[2];
      #pragma unroll
      for (int mt=0;mt<4;++mt)
        ap[mt] = *(const bf16x8*)&slotA[(mt*16+rowa)*40 + kg*8];
      #pragma unroll
      for (int nt=0;nt<2;++nt)
        bv[nt] = *(const bf16x8*)&slotB[(nt*16+rowa)*72 + 32 + kg*8];
      #pragma unroll
      for (int mt=0;mt<4;++mt)
        #pragma unroll
        for (int nt=0;nt<2;++nt)
          oacc[mt][nt] = __builtin_amdgcn_mfma_f32_16x16x32_bf16(ap[mt], bv[nt], oacc[mt][nt], 0, 0, 0);
    }

    // ---- o write (32B runs) ----
    #pragma unroll
    for (int nt=0;nt<2;++nt)
      #pragma unroll
      for (int mt=0;mt<4;++mt)
        #pragma unroll
        for (int i=0;i<4;++i)
          o_g[(wi64 + mt*16 + kg*4 + i)*256 + hc + nt*16 + rowa] = f2bf(oacc[mt][nt][i]);
  }
}

// ---------------- K2: out-proj + residual(regs) + LN2 + MLP + scatter ----------------
// LDS: Y h2 [64][264] 33792 | X: win2 stage -> 2x m-half [64][136] (34816) | red 4096 = 72704
#define K2_OFF_X   33792
#define K2_OFF_RED 68608
#define K2_SMEM    72704

__global__ __launch_bounds__(512, 4)
void mlp_kernel(const short* __restrict__ o_g, const float* __restrict__ x,
                const float* __restrict__ outb, const short* __restrict__ wout,
                const float* __restrict__ ln2w, const float* __restrict__ ln2b,
                const float* __restrict__ b1, const float* __restrict__ b2,
                const short* __restrict__ w1, const short* __restrict__ w2,
                float* __restrict__ out){
  __shared__ char smem[K2_SMEM];
  short* Y = (short*)smem;                 // h2
  short* X = (short*)(smem + K2_OFF_X);    // win2 stage -> m ping-pong
  float* red_s  = (float*)(smem + K2_OFF_RED);  // [512]
  float* red_q2 = red_s + 512;
  const int tid = threadIdx.x, w = tid >> 6, ln = tid & 63;
  const int rowa = ln & 15, kg = ln >> 4;
  const int wi = blockIdx.x, wi64 = wi*64;
  const int b = wi >> 8, wh = (wi >> 4) & 15, ww = wi & 15;
  const int xbase = b << 22;

  // ---- out-proj: A from global o, B = wout ----
  f32x4 op[4][2];
  #pragma unroll
  for (int mt=0;mt<4;++mt){ op[mt][0]=(f32x4){0,0,0,0}; op[mt][1]=(f32x4){0,0,0,0}; }
  #pragma unroll
  for (int kt=0;kt<8;++kt){
    bf16x8 ao[4], bw[2];
    #pragma unroll
    for (int mt=0;mt<4;++mt)
      ao[mt] = *(const bf16x8*)&o_g[(wi64 + mt*16+rowa)*256 + kt*32 + kg*8];
    #pragma unroll
    for (int nt=0;nt<2;++nt)
      bw[nt] = *(const bf16x8*)&wout[(w*32 + nt*16+rowa)*256 + kt*32 + kg*8];
    #pragma unroll
    for (int mt=0;mt<4;++mt)
      #pragma unroll
      for (int nt=0;nt<2;++nt)
        op[mt][nt] = __builtin_amdgcn_mfma_f32_16x16x32_bf16(ao[mt], bw[nt], op[mt][nt], 0, 0, 0);
  }

  // ---- win2 = proj + bias + x (fp32 kept in regs for final residual) ----
  float resf[4][2][4];
  #pragma unroll
  for (int nt=0;nt<2;++nt){
    const int col = w*32 + nt*16 + rowa;
    const float bias = outb[col];
    #pragma unroll
    for (int mt=0;mt<4;++mt){
      #pragma unroll
      for (int i=0;i<4;++i){
        const int row = mt*16 + kg*4 + i;
        const int r = row >> 3, cw = row & 7;
        const int hh = (wh*8 + r + 4) & 127;
        const int wc = (ww*8 + cw + 4) & 127;
        float v = op[mt][nt][i] + bias + x[xbase + (col << 14) + hh*128 + wc];
        resf[mt][nt][i] = v;
        X[row*LDH + col] = f2bf(v);
      }
    }
  }
  __syncthreads();

  // ---- LN2 from X -> h2 in Y ----
  {
    bf16x8 vv[4];
    float s = 0.f, sq = 0.f;
    #pragma unroll
    for (int q=0;q<4;++q){
      vv[q] = *(const bf16x8*)&X[ln*LDH + w*32 + q*8];
      #pragma unroll
      for (int e=0;e<8;++e){ float f = bf2f(vv[q][e]); s += f; sq += f*f; }
    }
    red_s[w*64 + ln] = s; red_q2[w*64 + ln] = sq;
    __syncthreads();
    float sum = 0.f, ssq = 0.f;
    #pragma unroll
    for (int j=0;j<8;++j){ sum += red_s[j*64 + ln]; ssq += red_q2[j*64 + ln]; }
    float mean = sum * 0.00390625f;
    float var  = ssq * 0.00390625f - mean*mean;
    float rstd = rsqrtf(var + 1e-5f);
    #pragma unroll
    for (int q=0;q<4;++q){
      bf16x8 pk;
      #pragma unroll
      for (int e=0;e<8;++e){
        const int c = w*32 + q*8 + e;
        pk[e] = f2bf((bf2f(vv[q][e]) - mean) * rstd * ln2w[c] + ln2b[c]);
      }
      *(bf16x8*)&Y[ln*LDH + w*32 + q*8] = pk;
    }
  }
  __syncthreads();   // h2 ready; X free (LN2 reads done)

  // ---- MLP: 8 half-chunks of 128 hidden, ping-pong m in X halves [64][136] ----
  f32x4 acc2[4][2];
  #pragma unroll
  for (int mt=0;mt<4;++mt){ acc2[mt][0]=(f32x4){0,0,0,0}; acc2[mt][1]=(f32x4){0,0,0,0}; }

  for (int hc2 = 0; hc2 < 8; ++hc2){
    short* mb = X + (hc2 & 1) * 8704;   // [64][136] shorts
    f32x4 a1[4];
    #pragma unroll
    for (int mt=0;mt<4;++mt) a1[mt] = (f32x4){0,0,0,0};
    #pragma unroll
    for (int kt=0;kt<8;++kt){
      bf16x8 ah[4], bw1;
      #pragma unroll
      for (int mt=0;mt<4;++mt)
        ah[mt] = *(const bf16x8*)&Y[(mt*16+rowa)*LDH + kt*32 + kg*8];
      bw1 = *(const bf16x8*)&w1[(hc2*128 + w*16 + rowa)*256 + kt*32 + kg*8];
      #pragma unroll
      for (int mt=0;mt<4;++mt)
        a1[mt] = __builtin_amdgcn_mfma_f32_16x16x32_bf16(ah[mt], bw1, a1[mt], 0, 0, 0);
    }
    {
      const float bias1 = b1[hc2*128 + w*16 + rowa];
      #pragma unroll
      for (int mt=0;mt<4;++mt)
        #pragma unroll
        for (int i=0;i<4;++i)
          mb[(mt*16 + kg*4 + i)*136 + w*16 + rowa] = f2bf(gelu_f(a1[mt][i] + bias1));
    }
    __syncthreads();   // m half visible; prev-prev buffer reads were fenced 2 syncs ago
    #pragma unroll
    for (int kt2=0;kt2<4;++kt2){
      bf16x8 am[4], bw2[2];
      #pragma unroll
      for (int mt=0;mt<4;++mt)
        am[mt] = *(const bf16x8*)&mb[(mt*16+rowa)*136 + kt2*32 + kg*8];
      #pragma unroll
      for (int nt=0;nt<2;++nt)
        bw2[nt] = *(const bf16x8*)&w2[(w*32 + nt*16+rowa)*1024 + hc2*128 + kt2*32 + kg*8];
      #pragma unroll
      for (int mt=0;mt<4;++mt)
        #pragma unroll
        for (int nt=0;nt<2;++nt)
          acc2[mt][nt] = __builtin_amdgcn_mfma_f32_16x16x32_bf16(am[mt], bw2[nt], acc2[mt][nt], 0, 0, 0);
    }
  }

  // ---- epilogue: + b2 + residual(regs), NCHW scatter with unshift ----
  #pragma unroll
  for (int nt=0;nt<2;++nt){
    const int col = w*32 + nt*16 + rowa;
    const float bias = b2[col];
    #pragma unroll
    for (int mt=0;mt<4;++mt){
      #pragma unroll
      for (int i=0;i<4;++i){
        const int row = mt*16 + kg*4 + i;
        const int r = row >> 3, cw = row & 7;
        const int hh = (wh*8 + r + 4) & 127;
        const int wc = (ww*8 + cw + 4) & 127;
        out[(((b<<8) + col) << 14) + hh*128 + wc] = acc2[mt][nt][i] + bias + resf[mt][nt][i];
      }
    }
  }
}

// ---------------- launch ----------------
extern "C" void kernel_launch(void* const* d_in, const int* in_sizes, int n_in,
                              void* d_out, int out_size, void* d_ws, size_t ws_size,
                              hipStream_t stream) {
  (void)in_sizes; (void)n_in; (void)out_size; (void)ws_size;
  const float* x    = (const float*)d_in[0];
  const float* ln1w = (const float*)d_in[1];
  const float* ln1b = (const float*)d_in[2];
  const float* inw  = (const float*)d_in[3];
  const float* inb  = (const float*)d_in[4];
  const float* outw = (const float*)d_in[5];
  const float* outb = (const float*)d_in[6];
  const float* ln2w = (const float*)d_in[7];
  const float* ln2b = (const float*)d_in[8];
  const float* w1f  = (const float*)d_in[9];
  const float* b1   = (const float*)d_in[10];
  const float* w2f  = (const float*)d_in[11];
  const float* b2   = (const float*)d_in[12];
  float* out = (float*)d_out;

  short* ws    = (short*)d_ws;
  short* wqkv  = ws;            // 768*256
  short* wout  = ws + 196608;   // 256*256
  short* w1b   = ws + 262144;   // 1024*256
  short* w2b   = ws + 524288;   // 256*1024
  short* o_g   = ws + 786432;   // 2048*64*256 bf16 (attention output)
  short* h_g   = (short*)d_out; // 2048*64*256 bf16 in first half of out buffer
                                // (dead before mlp_kernel overwrites out; stream-ordered)

  hipLaunchKernelGGL(wconv_kernel, dim3(3072), dim3(256), 0, stream, inw, outw, w1f, w2f, ws);
  hipLaunchKernelGGL(ln1_kernel,   dim3(2048), dim3(256), 0, stream, x, ln1w, ln1b, h_g);
  hipLaunchKernelGGL(attn_kernel,  dim3(2048), dim3(256), 0, stream, h_g, inb, wqkv, o_g);
  hipLaunchKernelGGL(mlp_kernel,   dim3(2048), dim3(512), 0, stream,
                     o_g, x, outb, wout, ln2w, ln2b, b1, b2, w1b, w2b, out);
}

// Round 4
// 822.731 us; speedup vs baseline: 1.1865x; 1.1865x over previous
//
#include <hip/hip_runtime.h>
#include <math.h>

// Swin block: B=8, C=256, H=W=128, WS=8, SS=4, NH=8, dh=32
// 2048 windows x 64 tokens x 256 ch. All matmuls via mfma_f32_16x16x32_bf16.

#define LDH 264   // bf16 row stride for [64][256] tiles
#define LDS_S 40  // bf16 row stride for per-wave [64][40] slots
#define LDM 136   // bf16 row stride for m chunk [64][128]

typedef __attribute__((ext_vector_type(8))) short bf16x8;
typedef __attribute__((ext_vector_type(4))) short bf16x4;
typedef __attribute__((ext_vector_type(4))) float f32x4;

static __device__ __forceinline__ float bf2f(short s){
  union { unsigned u; float f; } cv;
  cv.u = ((unsigned)(unsigned short)s) << 16;
  return cv.f;
}
static __device__ __forceinline__ short f2bf(float f){
  union { float f; unsigned u; } cv; cv.f = f;
  unsigned r = (cv.u + 0x7FFFu + ((cv.u >> 16) & 1u)) >> 16;  // RNE
  return (short)r;
}
static __device__ __forceinline__ float gelu_f(float x){
  return 0.5f * x * (1.0f + erff(x * 0.7071067811865475f));
}

// ---------------- K0: merged fp32 -> bf16 weight convert ----------------
__global__ void wconv_kernel(const float* __restrict__ inw, const float* __restrict__ outw,
                             const float* __restrict__ w1f, const float* __restrict__ w2f,
                             short* __restrict__ dst){
  int i = blockIdx.x * 256 + threadIdx.x;   // grid covers exactly 786432
  const float* s; int off;
  if (i < 196608){ s = inw;  off = 0; }
  else if (i < 262144){ s = outw; off = 196608; }
  else if (i < 524288){ s = w1f;  off = 262144; }
  else { s = w2f; off = 524288; }
  dst[i] = f2bf(s[i - off]);
}

// [64x256] @ [256 x 32] GEMM helper: A from sh_h, B rows wrowbase.. of w (bf16 [.][256])
__device__ __forceinline__ void gemm_h_w32(const short* __restrict__ sh_h,
                                           const short* __restrict__ w, int wrowbase,
                                           int rowa, int kg, f32x4 acc[4][2]){
  #pragma unroll
  for (int kt = 0; kt < 8; ++kt){
    bf16x8 av[4], bw[2];
    #pragma unroll
    for (int mt=0;mt<4;++mt)
      av[mt] = *(const bf16x8*)&sh_h[(mt*16+rowa)*LDH + kt*32 + kg*8];
    #pragma unroll
    for (int nt=0;nt<2;++nt)
      bw[nt] = *(const bf16x8*)&w[(wrowbase + nt*16 + rowa)*256 + kt*32 + kg*8];
    #pragma unroll
    for (int mt=0;mt<4;++mt)
      #pragma unroll
      for (int nt=0;nt<2;++nt)
        acc[mt][nt] = __builtin_amdgcn_mfma_f32_16x16x32_bf16(av[mt], bw[nt], acc[mt][nt], 0, 0, 0);
  }
}

// ---------------- kernel 1: LN1 + QKV + attention + out-proj + residual (round-2, proven) ----
#define K1_OFF_WV  33792
#define K1_OFF_RED 74752
#define K1_SMEM    76800

__global__ __launch_bounds__(256, 2)
void swin_attn_kernel(const float* __restrict__ x,
                      const float* __restrict__ ln1w, const float* __restrict__ ln1b,
                      const float* __restrict__ inb,  const float* __restrict__ outb,
                      const short* __restrict__ wqkv, const short* __restrict__ wout,
                      short* __restrict__ win2)
{
  __shared__ char smem[K1_SMEM];
  short* sh_h   = (short*)smem;
  float* red_s  = (float*)(smem + K1_OFF_RED);
  float* red_q2 = red_s + 256;

  const int tid = threadIdx.x;
  const int wv  = tid >> 6;
  const int ln  = tid & 63;
  const int rowa = ln & 15;
  const int kg   = ln >> 4;

  short* slotA = (short*)(smem + K1_OFF_WV) + wv*5120;  // [64][40]
  short* slotB = slotA + 2560;                          // [64][40]

  const int wi = blockIdx.x;
  const int b  = wi >> 8;
  const int wh = (wi >> 4) & 15;
  const int ww = wi & 15;

  const int hh = (wh*8 + (ln >> 3) + 4) & 127;   // roll(-4)
  const int wc = (ww*8 + (ln & 7) + 4) & 127;
  const int offhw = hh*128 + wc;
  const int xbase = b << 22;

  // ---- LN1 (values in regs) ----
  {
    const int cbeg = wv*64;
    float vals[64];
    float s = 0.f, sq = 0.f;
    #pragma unroll
    for (int j = 0; j < 64; ++j){
      float v = x[xbase + ((cbeg + j) << 14) + offhw];
      vals[j] = v; s += v; sq += v*v;
    }
    red_s[cbeg + ln]  = s;
    red_q2[cbeg + ln] = sq;
    __syncthreads();
    float sum = red_s[ln] + red_s[64+ln] + red_s[128+ln] + red_s[192+ln];
    float ssq = red_q2[ln] + red_q2[64+ln] + red_q2[128+ln] + red_q2[192+ln];
    float mean = sum * 0.00390625f;
    float var  = ssq * 0.00390625f - mean*mean;
    float rstd = rsqrtf(var + 1e-5f);
    #pragma unroll
    for (int j = 0; j < 64; ++j){
      const int c = cbeg + j;
      sh_h[ln*LDH + c] = f2bf((vals[j] - mean) * rstd * ln1w[c] + ln1b[c]);
    }
  }
  __syncthreads();

  // ---- per-wave, per-head attention; wave wv owns heads 2wv, 2wv+1 ----
  const float scale = 0.1767766952966369f;  // 1/sqrt(32)
  f32x4 oacc[4][4];
  #pragma unroll
  for (int mt=0;mt<4;++mt)
    #pragma unroll
    for (int j=0;j<4;++j)
      oacc[mt][j] = (f32x4){0.f,0.f,0.f,0.f};

  #pragma unroll
  for (int hd = 0; hd < 2; ++hd){
    const int hc = (2*wv + hd) * 32;

    // q -> slotA
    {
      f32x4 accq[4][2];
      #pragma unroll
      for (int mt=0;mt<4;++mt){ accq[mt][0]=(f32x4){0,0,0,0}; accq[mt][1]=(f32x4){0,0,0,0}; }
      gemm_h_w32(sh_h, wqkv, 0*256 + hc, rowa, kg, accq);
      #pragma unroll
      for (int nt=0;nt<2;++nt){
        const float bias = inb[hc + nt*16 + rowa];
        #pragma unroll
        for (int mt=0;mt<4;++mt)
          #pragma unroll
          for (int i=0;i<4;++i)
            slotA[(mt*16 + kg*4 + i)*LDS_S + nt*16 + rowa] = f2bf(accq[mt][nt][i] + bias);
      }
    }
    // k -> slotB
    {
      f32x4 acck[4][2];
      #pragma unroll
      for (int mt=0;mt<4;++mt){ acck[mt][0]=(f32x4){0,0,0,0}; acck[mt][1]=(f32x4){0,0,0,0}; }
      gemm_h_w32(sh_h, wqkv, 1*256 + hc, rowa, kg, acck);
      #pragma unroll
      for (int nt=0;nt<2;++nt){
        const float bias = inb[256 + hc + nt*16 + rowa];
        #pragma unroll
        for (int mt=0;mt<4;++mt)
          #pragma unroll
          for (int i=0;i<4;++i)
            slotB[(mt*16 + kg*4 + i)*LDS_S + nt*16 + rowa] = f2bf(acck[mt][nt][i] + bias);
      }
    }

    // S = q @ k^T
    f32x4 sacc[4][4];
    #pragma unroll
    for (int mt=0;mt<4;++mt)
      #pragma unroll
      for (int nt=0;nt<4;++nt)
        sacc[mt][nt] = (f32x4){0.f,0.f,0.f,0.f};
    {
      bf16x8 aq[4], bk[4];
      #pragma unroll
      for (int mt=0;mt<4;++mt)
        aq[mt] = *(const bf16x8*)&slotA[(mt*16+rowa)*LDS_S + kg*8];
      #pragma unroll
      for (int nt=0;nt<4;++nt)
        bk[nt] = *(const bf16x8*)&slotB[(nt*16+rowa)*LDS_S + kg*8];
      #pragma unroll
      for (int mt=0;mt<4;++mt)
        #pragma unroll
        for (int nt=0;nt<4;++nt)
          sacc[mt][nt] = __builtin_amdgcn_mfma_f32_16x16x32_bf16(aq[mt], bk[nt], sacc[mt][nt], 0, 0, 0);
    }

    // v -> vT in slotB
    {
      f32x4 accv[4][2];
      #pragma unroll
      for (int mt=0;mt<4;++mt){ accv[mt][0]=(f32x4){0,0,0,0}; accv[mt][1]=(f32x4){0,0,0,0}; }
      gemm_h_w32(sh_h, wqkv, 2*256 + hc, rowa, kg, accv);
      #pragma unroll
      for (int nt=0;nt<2;++nt){
        const float bias = inb[512 + hc + nt*16 + rowa];
        #pragma unroll
        for (int mt=0;mt<4;++mt)
          #pragma unroll
          for (int i=0;i<4;++i)
            slotB[(nt*16 + rowa)*LDS_S + mt*16 + kg*4 + i] = f2bf(accv[mt][nt][i] + bias);  // [ch][tok]
      }
    }

    // softmax
    #pragma unroll
    for (int mt=0;mt<4;++mt){
      #pragma unroll
      for (int i=0;i<4;++i){
        float v0 = sacc[mt][0][i]*scale;
        float v1 = sacc[mt][1][i]*scale;
        float v2 = sacc[mt][2][i]*scale;
        float v3 = sacc[mt][3][i]*scale;
        float mx = fmaxf(fmaxf(v0,v1), fmaxf(v2,v3));
        #pragma unroll
        for (int d=1; d<16; d<<=1) mx = fmaxf(mx, __shfl_xor(mx, d, 64));
        v0 = __expf(v0-mx); v1 = __expf(v1-mx); v2 = __expf(v2-mx); v3 = __expf(v3-mx);
        float sm = v0+v1+v2+v3;
        #pragma unroll
        for (int d=1; d<16; d<<=1) sm += __shfl_xor(sm, d, 64);
        const float inv = 1.f / sm;
        sacc[mt][0][i] = v0*inv; sacc[mt][1][i] = v1*inv;
        sacc[mt][2][i] = v2*inv; sacc[mt][3][i] = v3*inv;
      }
    }

    // PV in two kv-chunks of 32, P through slotA
    #pragma unroll
    for (int ck=0; ck<2; ++ck){
      #pragma unroll
      for (int ntl=0; ntl<2; ++ntl)
        #pragma unroll
        for (int mt=0;mt<4;++mt)
          #pragma unroll
          for (int i=0;i<4;++i)
            slotA[(mt*16 + kg*4 + i)*LDS_S + ntl*16 + rowa] = f2bf(sacc[mt][2*ck+ntl][i]);
      bf16x8 ap[4], bv[2];
      #pragma unroll
      for (int mt=0;mt<4;++mt)
        ap[mt] = *(const bf16x8*)&slotA[(mt*16+rowa)*LDS_S + kg*8];
      #pragma unroll
      for (int nt=0;nt<2;++nt)
        bv[nt] = *(const bf16x8*)&slotB[(nt*16+rowa)*LDS_S + kg*8];
      #pragma unroll
      for (int mt=0;mt<4;++mt)
        #pragma unroll
        for (int nt=0;nt<2;++nt)
          oacc[mt][hd*2+nt] = __builtin_amdgcn_mfma_f32_16x16x32_bf16(ap[mt], bv[nt], oacc[mt][hd*2+nt], 0, 0, 0);
    }
  }

  __syncthreads();   // all waves done with h -> region becomes o

  #pragma unroll
  for (int j=0;j<4;++j){
    const int col = wv*64 + j*16 + rowa;
    #pragma unroll
    for (int mt=0;mt<4;++mt)
      #pragma unroll
      for (int i=0;i<4;++i)
        sh_h[(mt*16 + kg*4 + i)*LDH + col] = f2bf(oacc[mt][j][i]);
  }
  __syncthreads();

  // ---- out-proj + bias + residual(global x) -> win2 ----
  {
    f32x4 acc[4][4];
    #pragma unroll
    for (int mt=0;mt<4;++mt)
      #pragma unroll
      for (int nt=0;nt<4;++nt)
        acc[mt][nt] = (f32x4){0.f,0.f,0.f,0.f};
    for (int kt=0; kt<8; ++kt){
      bf16x8 av[4], bw[4];
      #pragma unroll
      for (int mt=0;mt<4;++mt)
        av[mt] = *(const bf16x8*)&sh_h[(mt*16+rowa)*LDH + kt*32 + kg*8];
      #pragma unroll
      for (int nt=0;nt<4;++nt)
        bw[nt] = *(const bf16x8*)&wout[(wv*64 + nt*16 + rowa)*256 + kt*32 + kg*8];
      #pragma unroll
      for (int mt=0;mt<4;++mt)
        #pragma unroll
        for (int nt=0;nt<4;++nt)
          acc[mt][nt] = __builtin_amdgcn_mfma_f32_16x16x32_bf16(av[mt], bw[nt], acc[mt][nt], 0, 0, 0);
    }
    #pragma unroll
    for (int nt=0;nt<4;++nt){
      const int col = wv*64 + nt*16 + rowa;
      const float bias = outb[col];
      #pragma unroll
      for (int mt=0;mt<4;++mt){
        #pragma unroll
        for (int i=0;i<4;++i){
          const int row = mt*16 + kg*4 + i;
          const int r = row >> 3, cw = row & 7;
          const int hh2 = (wh*8 + r + 4) & 127;
          const int wc2 = (ww*8 + cw + 4) & 127;
          const float res = x[xbase + (col << 14) + hh2*128 + wc2];
          win2[(wi*64 + row)*256 + col] = f2bf(acc[mt][nt][i] + bias + res);
        }
      }
    }
  }
}

// ---------------- kernel 2: LN2 + MLP + residual + NCHW scatter ----------------
// LDS (53248 B -> 3 blocks/CU):
//   [0,     33792)  Y: h2 bf16 [64][264]
//   [33792, 51200)  M: m chunk bf16 [64][136] (128 hidden)
//   [51200, 53248)  reduce scratch 2x[256] f32
#define K2_OFF_M   33792
#define K2_OFF_RED 51200
#define K2_SMEM    53248

__global__ __launch_bounds__(256, 3)
void swin_mlp_kernel(const short* __restrict__ win2,
                     const float* __restrict__ ln2w, const float* __restrict__ ln2b,
                     const float* __restrict__ b1,   const float* __restrict__ b2,
                     const short* __restrict__ w1,   const short* __restrict__ w2,
                     float* __restrict__ out)
{
  __shared__ char smem[K2_SMEM];
  short* Y = (short*)smem;
  short* M = (short*)(smem + K2_OFF_M);
  float* red_s  = (float*)(smem + K2_OFF_RED);
  float* red_q2 = red_s + 256;

  const int tid = threadIdx.x;
  const int wv  = tid >> 6;
  const int ln  = tid & 63;
  const int rowa = ln & 15;
  const int kg   = ln >> 4;
  const int wi = blockIdx.x;
  const int wbase = wi * (64*256);

  // ---- LN2 straight from global win2 -> h2 in Y (same value order as round-2) ----
  {
    bf16x8 vv[8];
    float s = 0.f, sq = 0.f;
    const int cbeg = wv*64;
    #pragma unroll
    for (int q=0;q<8;++q){
      vv[q] = *(const bf16x8*)&win2[wbase + ln*256 + cbeg + q*8];
      #pragma unroll
      for (int e=0;e<8;++e){ float f = bf2f(vv[q][e]); s += f; sq += f*f; }
    }
    red_s[cbeg + ln]  = s;
    red_q2[cbeg + ln] = sq;
    __syncthreads();
    float sum = red_s[ln] + red_s[64+ln] + red_s[128+ln] + red_s[192+ln];
    float ssq = red_q2[ln] + red_q2[64+ln] + red_q2[128+ln] + red_q2[192+ln];
    float mean = sum * 0.00390625f;
    float var  = ssq * 0.00390625f - mean*mean;
    float rstd = rsqrtf(var + 1e-5f);
    #pragma unroll
    for (int q=0;q<8;++q){
      bf16x8 pk;
      #pragma unroll
      for (int e=0;e<8;++e){
        const int c = cbeg + q*8 + e;
        pk[e] = f2bf((bf2f(vv[q][e]) - mean) * rstd * ln2w[c] + ln2b[c]);
      }
      *(bf16x8*)&Y[ln*LDH + cbeg + q*8] = pk;
    }
  }
  __syncthreads();

  // ---- MLP: 8 chunks of 128 hidden ----
  // GEMM1 operand-swapped: mfma(w1_frag, h2_frag) -> D[hid][tok]; thread holds 4 consecutive
  // hid per (rt,ct) -> b64-packed m writes. Bit-identical values to A/B-unswapped form.
  f32x4 acc2[4][4];
  #pragma unroll
  for (int mt=0;mt<4;++mt)
    #pragma unroll
    for (int nt=0;nt<4;++nt)
      acc2[mt][nt] = (f32x4){0.f,0.f,0.f,0.f};

  for (int chk = 0; chk < 8; ++chk){
    f32x4 acc1[2][4];
    #pragma unroll
    for (int rt=0;rt<2;++rt)
      #pragma unroll
      for (int ct=0;ct<4;++ct)
        acc1[rt][ct] = (f32x4){0.f,0.f,0.f,0.f};
    #pragma unroll
    for (int kt=0;kt<8;++kt){
      bf16x8 aw[2], bh[4];
      #pragma unroll
      for (int rt=0;rt<2;++rt)
        aw[rt] = *(const bf16x8*)&w1[(chk*128 + wv*32 + rt*16 + rowa)*256 + kt*32 + kg*8];
      #pragma unroll
      for (int ct=0;ct<4;++ct)
        bh[ct] = *(const bf16x8*)&Y[(ct*16+rowa)*LDH + kt*32 + kg*8];
      #pragma unroll
      for (int rt=0;rt<2;++rt)
        #pragma unroll
        for (int ct=0;ct<4;++ct)
          acc1[rt][ct] = __builtin_amdgcn_mfma_f32_16x16x32_bf16(aw[rt], bh[ct], acc1[rt][ct], 0, 0, 0);
    }
    if (chk) __syncthreads();   // previous chunk's GEMM2 reads of M complete
    #pragma unroll
    for (int rt=0;rt<2;++rt){
      const int hidb = wv*32 + rt*16 + kg*4;       // hid within chunk
      const f32x4 b1v = *(const f32x4*)&b1[chk*128 + hidb];
      #pragma unroll
      for (int ct=0;ct<4;++ct){
        bf16x4 st;
        #pragma unroll
        for (int i=0;i<4;++i)
          st[i] = f2bf(gelu_f(acc1[rt][ct][i] + b1v[i]));
        *(bf16x4*)&M[(ct*16 + rowa)*LDM + hidb] = st;
      }
    }
    __syncthreads();   // m chunk visible
    #pragma unroll
    for (int kt2=0;kt2<4;++kt2){
      bf16x8 am[4], bw2[4];
      #pragma unroll
      for (int mt=0;mt<4;++mt)
        am[mt] = *(const bf16x8*)&M[(mt*16+rowa)*LDM + kt2*32 + kg*8];
      #pragma unroll
      for (int nt=0;nt<4;++nt)
        bw2[nt] = *(const bf16x8*)&w2[(wv*64 + nt*16+rowa)*1024 + chk*128 + kt2*32 + kg*8];
      #pragma unroll
      for (int mt=0;mt<4;++mt)
        #pragma unroll
        for (int nt=0;nt<4;++nt)
          acc2[mt][nt] = __builtin_amdgcn_mfma_f32_16x16x32_bf16(am[mt], bw2[nt], acc2[mt][nt], 0, 0, 0);
    }
  }

  // ---- epilogue: + b2 + win2 residual (global), NCHW scatter with unshift ----
  const int b  = wi >> 8;
  const int wh = (wi >> 4) & 15;
  const int ww = wi & 15;
  #pragma unroll
  for (int nt=0;nt<4;++nt){
    const int col = wv*64 + nt*16 + rowa;
    const float bias = b2[col];
    #pragma unroll
    for (int mt=0;mt<4;++mt){
      #pragma unroll
      for (int i=0;i<4;++i){
        const int row = mt*16 + kg*4 + i;
        float v = acc2[mt][nt][i] + bias + bf2f(win2[wbase + row*256 + col]);
        const int r = row >> 3, cw = row & 7;
        const int hh = (wh*8 + r + 4) & 127;
        const int wcc = (ww*8 + cw + 4) & 127;
        out[(((b<<8) + col) << 14) + hh*128 + wcc] = v;
      }
    }
  }
}

// ---------------- launch ----------------
extern "C" void kernel_launch(void* const* d_in, const int* in_sizes, int n_in,
                              void* d_out, int out_size, void* d_ws, size_t ws_size,
                              hipStream_t stream) {
  (void)in_sizes; (void)n_in; (void)out_size; (void)ws_size;
  const float* x    = (const float*)d_in[0];
  const float* ln1w = (const float*)d_in[1];
  const float* ln1b = (const float*)d_in[2];
  const float* inw  = (const float*)d_in[3];
  const float* inb  = (const float*)d_in[4];
  const float* outw = (const float*)d_in[5];
  const float* outb = (const float*)d_in[6];
  const float* ln2w = (const float*)d_in[7];
  const float* ln2b = (const float*)d_in[8];
  const float* w1f  = (const float*)d_in[9];
  const float* b1   = (const float*)d_in[10];
  const float* w2f  = (const float*)d_in[11];
  const float* b2   = (const float*)d_in[12];
  float* out = (float*)d_out;

  short* ws    = (short*)d_ws;
  short* wqkv  = ws;            // 768*256
  short* wout  = ws + 196608;   // 256*256
  short* w1b   = ws + 262144;   // 1024*256
  short* w2b   = ws + 524288;   // 256*1024
  short* win2  = ws + 786432;   // 2048*64*256 bf16

  hipLaunchKernelGGL(wconv_kernel, dim3(3072), dim3(256), 0, stream, inw, outw, w1f, w2f, ws);
  hipLaunchKernelGGL(swin_attn_kernel, dim3(2048), dim3(256), 0, stream,
                     x, ln1w, ln1b, inb, outb, wqkv, wout, win2);
  hipLaunchKernelGGL(swin_mlp_kernel, dim3(2048), dim3(256), 0, stream,
                     win2, ln2w, ln2b, b1, b2, w1b, w2b, out);
}

// Round 5
// 788.602 us; speedup vs baseline: 1.2379x; 1.0433x over previous
//
#include <hip/hip_runtime.h>
#include <math.h>

// Swin block: B=8, C=256, H=W=128, WS=8, SS=4, NH=8, dh=32
// 2048 windows x 64 tokens x 256 ch. All matmuls via mfma_f32_16x16x32_bf16.

#define LDH 264   // bf16 row stride for [64][256] tiles
#define LDS_S 40  // bf16 row stride for per-wave [64][40] slots
#define LDM 136   // bf16 row stride for m chunk [64][128]

typedef __attribute__((ext_vector_type(8))) short bf16x8;
typedef __attribute__((ext_vector_type(4))) short bf16x4;
typedef __attribute__((ext_vector_type(4))) float f32x4;

static __device__ __forceinline__ float bf2f(short s){
  union { unsigned u; float f; } cv;
  cv.u = ((unsigned)(unsigned short)s) << 16;
  return cv.f;
}
static __device__ __forceinline__ short f2bf(float f){
  union { float f; unsigned u; } cv; cv.f = f;
  unsigned r = (cv.u + 0x7FFFu + ((cv.u >> 16) & 1u)) >> 16;  // RNE
  return (short)r;
}
static __device__ __forceinline__ float gelu_f(float x){
  return 0.5f * x * (1.0f + erff(x * 0.7071067811865475f));
}

// ---------------- K0: merged fp32 -> bf16 weight convert ----------------
__global__ void wconv_kernel(const float* __restrict__ inw, const float* __restrict__ outw,
                             const float* __restrict__ w1f, const float* __restrict__ w2f,
                             short* __restrict__ dst){
  int i = blockIdx.x * 256 + threadIdx.x;   // grid covers exactly 786432
  const float* s; int off;
  if (i < 196608){ s = inw;  off = 0; }
  else if (i < 262144){ s = outw; off = 196608; }
  else if (i < 524288){ s = w1f;  off = 262144; }
  else { s = w2f; off = 524288; }
  dst[i] = f2bf(s[i - off]);
}

// [64x256] @ [256 x 32] GEMM helper: A from sh_h, B rows wrowbase.. of w (bf16 [.][256])
__device__ __forceinline__ void gemm_h_w32(const short* __restrict__ sh_h,
                                           const short* __restrict__ w, int wrowbase,
                                           int rowa, int kg, f32x4 acc[4][2]){
  #pragma unroll
  for (int kt = 0; kt < 8; ++kt){
    bf16x8 av[4], bw[2];
    #pragma unroll
    for (int mt=0;mt<4;++mt)
      av[mt] = *(const bf16x8*)&sh_h[(mt*16+rowa)*LDH + kt*32 + kg*8];
    #pragma unroll
    for (int nt=0;nt<2;++nt)
      bw[nt] = *(const bf16x8*)&w[(wrowbase + nt*16 + rowa)*256 + kt*32 + kg*8];
    #pragma unroll
    for (int mt=0;mt<4;++mt)
      #pragma unroll
      for (int nt=0;nt<2;++nt)
        acc[mt][nt] = __builtin_amdgcn_mfma_f32_16x16x32_bf16(av[mt], bw[nt], acc[mt][nt], 0, 0, 0);
  }
}

// ---------------- kernel 1: LN1 + QKV + attention + out-proj + residual (round-2, proven) ----
#define K1_OFF_WV  33792
#define K1_OFF_RED 74752
#define K1_SMEM    76800

__global__ __launch_bounds__(256, 2)
void swin_attn_kernel(const float* __restrict__ x,
                      const float* __restrict__ ln1w, const float* __restrict__ ln1b,
                      const float* __restrict__ inb,  const float* __restrict__ outb,
                      const short* __restrict__ wqkv, const short* __restrict__ wout,
                      short* __restrict__ win2)
{
  __shared__ char smem[K1_SMEM];
  short* sh_h   = (short*)smem;
  float* red_s  = (float*)(smem + K1_OFF_RED);
  float* red_q2 = red_s + 256;

  const int tid = threadIdx.x;
  const int wv  = tid >> 6;
  const int ln  = tid & 63;
  const int rowa = ln & 15;
  const int kg   = ln >> 4;

  short* slotA = (short*)(smem + K1_OFF_WV) + wv*5120;  // [64][40]
  short* slotB = slotA + 2560;                          // [64][40]

  const int wi = blockIdx.x;
  const int b  = wi >> 8;
  const int wh = (wi >> 4) & 15;
  const int ww = wi & 15;

  const int hh = (wh*8 + (ln >> 3) + 4) & 127;   // roll(-4)
  const int wc = (ww*8 + (ln & 7) + 4) & 127;
  const int offhw = hh*128 + wc;
  const int xbase = b << 22;

  // ---- LN1 (values in regs) ----
  {
    const int cbeg = wv*64;
    float vals[64];
    float s = 0.f, sq = 0.f;
    #pragma unroll
    for (int j = 0; j < 64; ++j){
      float v = x[xbase + ((cbeg + j) << 14) + offhw];
      vals[j] = v; s += v; sq += v*v;
    }
    red_s[cbeg + ln]  = s;
    red_q2[cbeg + ln] = sq;
    __syncthreads();
    float sum = red_s[ln] + red_s[64+ln] + red_s[128+ln] + red_s[192+ln];
    float ssq = red_q2[ln] + red_q2[64+ln] + red_q2[128+ln] + red_q2[192+ln];
    float mean = sum * 0.00390625f;
    float var  = ssq * 0.00390625f - mean*mean;
    float rstd = rsqrtf(var + 1e-5f);
    #pragma unroll
    for (int j = 0; j < 64; ++j){
      const int c = cbeg + j;
      sh_h[ln*LDH + c] = f2bf((vals[j] - mean) * rstd * ln1w[c] + ln1b[c]);
    }
  }
  __syncthreads();

  // ---- per-wave, per-head attention; wave wv owns heads 2wv, 2wv+1 ----
  const float scale = 0.1767766952966369f;  // 1/sqrt(32)
  f32x4 oacc[4][4];
  #pragma unroll
  for (int mt=0;mt<4;++mt)
    #pragma unroll
    for (int j=0;j<4;++j)
      oacc[mt][j] = (f32x4){0.f,0.f,0.f,0.f};

  #pragma unroll
  for (int hd = 0; hd < 2; ++hd){
    const int hc = (2*wv + hd) * 32;

    // q -> slotA
    {
      f32x4 accq[4][2];
      #pragma unroll
      for (int mt=0;mt<4;++mt){ accq[mt][0]=(f32x4){0,0,0,0}; accq[mt][1]=(f32x4){0,0,0,0}; }
      gemm_h_w32(sh_h, wqkv, 0*256 + hc, rowa, kg, accq);
      #pragma unroll
      for (int nt=0;nt<2;++nt){
        const float bias = inb[hc + nt*16 + rowa];
        #pragma unroll
        for (int mt=0;mt<4;++mt)
          #pragma unroll
          for (int i=0;i<4;++i)
            slotA[(mt*16 + kg*4 + i)*LDS_S + nt*16 + rowa] = f2bf(accq[mt][nt][i] + bias);
      }
    }
    // k -> slotB
    {
      f32x4 acck[4][2];
      #pragma unroll
      for (int mt=0;mt<4;++mt){ acck[mt][0]=(f32x4){0,0,0,0}; acck[mt][1]=(f32x4){0,0,0,0}; }
      gemm_h_w32(sh_h, wqkv, 1*256 + hc, rowa, kg, acck);
      #pragma unroll
      for (int nt=0;nt<2;++nt){
        const float bias = inb[256 + hc + nt*16 + rowa];
        #pragma unroll
        for (int mt=0;mt<4;++mt)
          #pragma unroll
          for (int i=0;i<4;++i)
            slotB[(mt*16 + kg*4 + i)*LDS_S + nt*16 + rowa] = f2bf(acck[mt][nt][i] + bias);
      }
    }

    // S = q @ k^T
    f32x4 sacc[4][4];
    #pragma unroll
    for (int mt=0;mt<4;++mt)
      #pragma unroll
      for (int nt=0;nt<4;++nt)
        sacc[mt][nt] = (f32x4){0.f,0.f,0.f,0.f};
    {
      bf16x8 aq[4], bk[4];
      #pragma unroll
      for (int mt=0;mt<4;++mt)
        aq[mt] = *(const bf16x8*)&slotA[(mt*16+rowa)*LDS_S + kg*8];
      #pragma unroll
      for (int nt=0;nt<4;++nt)
        bk[nt] = *(const bf16x8*)&slotB[(nt*16+rowa)*LDS_S + kg*8];
      #pragma unroll
      for (int mt=0;mt<4;++mt)
        #pragma unroll
        for (int nt=0;nt<4;++nt)
          sacc[mt][nt] = __builtin_amdgcn_mfma_f32_16x16x32_bf16(aq[mt], bk[nt], sacc[mt][nt], 0, 0, 0);
    }

    // v -> vT in slotB
    {
      f32x4 accv[4][2];
      #pragma unroll
      for (int mt=0;mt<4;++mt){ accv[mt][0]=(f32x4){0,0,0,0}; accv[mt][1]=(f32x4){0,0,0,0}; }
      gemm_h_w32(sh_h, wqkv, 2*256 + hc, rowa, kg, accv);
      #pragma unroll
      for (int nt=0;nt<2;++nt){
        const float bias = inb[512 + hc + nt*16 + rowa];
        #pragma unroll
        for (int mt=0;mt<4;++mt)
          #pragma unroll
          for (int i=0;i<4;++i)
            slotB[(nt*16 + rowa)*LDS_S + mt*16 + kg*4 + i] = f2bf(accv[mt][nt][i] + bias);  // [ch][tok]
      }
    }

    // softmax
    #pragma unroll
    for (int mt=0;mt<4;++mt){
      #pragma unroll
      for (int i=0;i<4;++i){
        float v0 = sacc[mt][0][i]*scale;
        float v1 = sacc[mt][1][i]*scale;
        float v2 = sacc[mt][2][i]*scale;
        float v3 = sacc[mt][3][i]*scale;
        float mx = fmaxf(fmaxf(v0,v1), fmaxf(v2,v3));
        #pragma unroll
        for (int d=1; d<16; d<<=1) mx = fmaxf(mx, __shfl_xor(mx, d, 64));
        v0 = __expf(v0-mx); v1 = __expf(v1-mx); v2 = __expf(v2-mx); v3 = __expf(v3-mx);
        float sm = v0+v1+v2+v3;
        #pragma unroll
        for (int d=1; d<16; d<<=1) sm += __shfl_xor(sm, d, 64);
        const float inv = 1.f / sm;
        sacc[mt][0][i] = v0*inv; sacc[mt][1][i] = v1*inv;
        sacc[mt][2][i] = v2*inv; sacc[mt][3][i] = v3*inv;
      }
    }

    // PV in two kv-chunks of 32, P through slotA
    #pragma unroll
    for (int ck=0; ck<2; ++ck){
      #pragma unroll
      for (int ntl=0; ntl<2; ++ntl)
        #pragma unroll
        for (int mt=0;mt<4;++mt)
          #pragma unroll
          for (int i=0;i<4;++i)
            slotA[(mt*16 + kg*4 + i)*LDS_S + ntl*16 + rowa] = f2bf(sacc[mt][2*ck+ntl][i]);
      bf16x8 ap[4], bv[2];
      #pragma unroll
      for (int mt=0;mt<4;++mt)
        ap[mt] = *(const bf16x8*)&slotA[(mt*16+rowa)*LDS_S + kg*8];
      #pragma unroll
      for (int nt=0;nt<2;++nt)
        bv[nt] = *(const bf16x8*)&slotB[(nt*16+rowa)*LDS_S + kg*8];
      #pragma unroll
      for (int mt=0;mt<4;++mt)
        #pragma unroll
        for (int nt=0;nt<2;++nt)
          oacc[mt][hd*2+nt] = __builtin_amdgcn_mfma_f32_16x16x32_bf16(ap[mt], bv[nt], oacc[mt][hd*2+nt], 0, 0, 0);
    }
  }

  __syncthreads();   // all waves done with h -> region becomes o

  #pragma unroll
  for (int j=0;j<4;++j){
    const int col = wv*64 + j*16 + rowa;
    #pragma unroll
    for (int mt=0;mt<4;++mt)
      #pragma unroll
      for (int i=0;i<4;++i)
        sh_h[(mt*16 + kg*4 + i)*LDH + col] = f2bf(oacc[mt][j][i]);
  }
  __syncthreads();

  // ---- out-proj + bias + residual(global x) -> win2 ----
  {
    f32x4 acc[4][4];
    #pragma unroll
    for (int mt=0;mt<4;++mt)
      #pragma unroll
      for (int nt=0;nt<4;++nt)
        acc[mt][nt] = (f32x4){0.f,0.f,0.f,0.f};
    for (int kt=0; kt<8; ++kt){
      bf16x8 av[4], bw[4];
      #pragma unroll
      for (int mt=0;mt<4;++mt)
        av[mt] = *(const bf16x8*)&sh_h[(mt*16+rowa)*LDH + kt*32 + kg*8];
      #pragma unroll
      for (int nt=0;nt<4;++nt)
        bw[nt] = *(const bf16x8*)&wout[(wv*64 + nt*16 + rowa)*256 + kt*32 + kg*8];
      #pragma unroll
      for (int mt=0;mt<4;++mt)
        #pragma unroll
        for (int nt=0;nt<4;++nt)
          acc[mt][nt] = __builtin_amdgcn_mfma_f32_16x16x32_bf16(av[mt], bw[nt], acc[mt][nt], 0, 0, 0);
    }
    #pragma unroll
    for (int nt=0;nt<4;++nt){
      const int col = wv*64 + nt*16 + rowa;
      const float bias = outb[col];
      #pragma unroll
      for (int mt=0;mt<4;++mt){
        #pragma unroll
        for (int i=0;i<4;++i){
          const int row = mt*16 + kg*4 + i;
          const int r = row >> 3, cw = row & 7;
          const int hh2 = (wh*8 + r + 4) & 127;
          const int wc2 = (ww*8 + cw + 4) & 127;
          const float res = x[xbase + (col << 14) + hh2*128 + wc2];
          win2[(wi*64 + row)*256 + col] = f2bf(acc[mt][nt][i] + bias + res);
        }
      }
    }
  }
}

// ---------------- kernel 2: LN2 + pipelined MLP + residual + NCHW scatter ----------------
// LDS (53248 B -> 3 blocks/CU):
//   [0,     33792)  Y: h2 bf16 [64][264]
//   [33792, 51200)  M: m chunk bf16 [64][136] (128 hidden)
//   [51200, 53248)  reduce scratch 2x[256] f32
#define K2_OFF_M   33792
#define K2_OFF_RED 51200
#define K2_SMEM    53248

// GEMM1(chunk): acc1[rt][ct] += w1-rows x Y-tokens (operand-swapped, D[hid][tok])
__device__ __forceinline__ void mlp_gemm1(const short* __restrict__ w1, const short* Y,
                                          int chk, int wv, int rowa, int kg,
                                          f32x4 acc1[2][4]){
  #pragma unroll
  for (int kt=0;kt<8;++kt){
    bf16x8 aw[2], bh[4];
    #pragma unroll
    for (int rt=0;rt<2;++rt)
      aw[rt] = *(const bf16x8*)&w1[(chk*128 + wv*32 + rt*16 + rowa)*256 + kt*32 + kg*8];
    #pragma unroll
    for (int ct=0;ct<4;++ct)
      bh[ct] = *(const bf16x8*)&Y[(ct*16+rowa)*LDH + kt*32 + kg*8];
    #pragma unroll
    for (int rt=0;rt<2;++rt)
      #pragma unroll
      for (int ct=0;ct<4;++ct)
        acc1[rt][ct] = __builtin_amdgcn_mfma_f32_16x16x32_bf16(aw[rt], bh[ct], acc1[rt][ct], 0, 0, 0);
  }
}

// GELU(acc1)+bias -> M (b64-packed writes, conflict-light)
__device__ __forceinline__ void mlp_gelu_store(short* M, const float* __restrict__ b1,
                                               int chk, int wv, int rowa, int kg,
                                               const f32x4 acc1[2][4]){
  #pragma unroll
  for (int rt=0;rt<2;++rt){
    const int hidb = wv*32 + rt*16 + kg*4;       // hid within chunk
    const f32x4 b1v = *(const f32x4*)&b1[chk*128 + hidb];
    #pragma unroll
    for (int ct=0;ct<4;++ct){
      bf16x4 st;
      #pragma unroll
      for (int i=0;i<4;++i)
        st[i] = f2bf(gelu_f(acc1[rt][ct][i] + b1v[i]));
      *(bf16x4*)&M[(ct*16 + rowa)*LDM + hidb] = st;
    }
  }
}

// GEMM2(chunk): acc2 += M-tokens x w2-rows
__device__ __forceinline__ void mlp_gemm2(const short* M, const short* __restrict__ w2,
                                          int chk, int wv, int rowa, int kg,
                                          f32x4 acc2[4][4]){
  #pragma unroll
  for (int kt2=0;kt2<4;++kt2){
    bf16x8 am[4], bw2[4];
    #pragma unroll
    for (int mt=0;mt<4;++mt)
      am[mt] = *(const bf16x8*)&M[(mt*16+rowa)*LDM + kt2*32 + kg*8];
    #pragma unroll
    for (int nt=0;nt<4;++nt)
      bw2[nt] = *(const bf16x8*)&w2[(wv*64 + nt*16+rowa)*1024 + chk*128 + kt2*32 + kg*8];
    #pragma unroll
    for (int mt=0;mt<4;++mt)
      #pragma unroll
      for (int nt=0;nt<4;++nt)
        acc2[mt][nt] = __builtin_amdgcn_mfma_f32_16x16x32_bf16(am[mt], bw2[nt], acc2[mt][nt], 0, 0, 0);
  }
}

__global__ __launch_bounds__(256, 3)
void swin_mlp_kernel(const short* __restrict__ win2,
                     const float* __restrict__ ln2w, const float* __restrict__ ln2b,
                     const float* __restrict__ b1,   const float* __restrict__ b2,
                     const short* __restrict__ w1,   const short* __restrict__ w2,
                     float* __restrict__ out)
{
  __shared__ char smem[K2_SMEM];
  short* Y = (short*)smem;
  short* M = (short*)(smem + K2_OFF_M);
  float* red_s  = (float*)(smem + K2_OFF_RED);
  float* red_q2 = red_s + 256;

  const int tid = threadIdx.x;
  const int wv  = tid >> 6;
  const int ln  = tid & 63;
  const int rowa = ln & 15;
  const int kg   = ln >> 4;
  const int wi = blockIdx.x;
  const int wbase = wi * (64*256);

  // ---- LN2 straight from global win2 -> h2 in Y (bit-identical to round-4) ----
  {
    bf16x8 vv[8];
    float s = 0.f, sq = 0.f;
    const int cbeg = wv*64;
    #pragma unroll
    for (int q=0;q<8;++q){
      vv[q] = *(const bf16x8*)&win2[wbase + ln*256 + cbeg + q*8];
      #pragma unroll
      for (int e=0;e<8;++e){ float f = bf2f(vv[q][e]); s += f; sq += f*f; }
    }
    red_s[cbeg + ln]  = s;
    red_q2[cbeg + ln] = sq;
    __syncthreads();
    float sum = red_s[ln] + red_s[64+ln] + red_s[128+ln] + red_s[192+ln];
    float ssq = red_q2[ln] + red_q2[64+ln] + red_q2[128+ln] + red_q2[192+ln];
    float mean = sum * 0.00390625f;
    float var  = ssq * 0.00390625f - mean*mean;
    float rstd = rsqrtf(var + 1e-5f);
    #pragma unroll
    for (int q=0;q<8;++q){
      bf16x8 pk;
      #pragma unroll
      for (int e=0;e<8;++e){
        const int c = cbeg + q*8 + e;
        pk[e] = f2bf((bf2f(vv[q][e]) - mean) * rstd * ln2w[c] + ln2b[c]);
      }
      *(bf16x8*)&Y[ln*LDH + cbeg + q*8] = pk;
    }
  }
  __syncthreads();

  // ---- pipelined MLP: GEMM1(c+1) overlaps GEMM2(c); M written behind one barrier ----
  f32x4 acc2[4][4];
  #pragma unroll
  for (int mt=0;mt<4;++mt)
    #pragma unroll
    for (int nt=0;nt<4;++nt)
      acc2[mt][nt] = (f32x4){0.f,0.f,0.f,0.f};

  // prologue: chunk 0 -> M
  {
    f32x4 acc1[2][4];
    #pragma unroll
    for (int rt=0;rt<2;++rt)
      #pragma unroll
      for (int ct=0;ct<4;++ct)
        acc1[rt][ct] = (f32x4){0.f,0.f,0.f,0.f};
    mlp_gemm1(w1, Y, 0, wv, rowa, kg, acc1);
    mlp_gelu_store(M, b1, 0, wv, rowa, kg, acc1);
  }
  __syncthreads();   // M(0) ready

  #pragma unroll
  for (int c = 0; c < 8; ++c){
    if (c < 7){
      f32x4 acc1n[2][4];
      #pragma unroll
      for (int rt=0;rt<2;++rt)
        #pragma unroll
        for (int ct=0;ct<4;++ct)
          acc1n[rt][ct] = (f32x4){0.f,0.f,0.f,0.f};
      // independent: GEMM1(c+1) into regs, GEMM2(c) from resident M — one dense window
      mlp_gemm1(w1, Y, c+1, wv, rowa, kg, acc1n);
      mlp_gemm2(M, w2, c, wv, rowa, kg, acc2);
      __syncthreads();   // all M(c) reads done
      mlp_gelu_store(M, b1, c+1, wv, rowa, kg, acc1n);
      __syncthreads();   // M(c+1) ready
    } else {
      mlp_gemm2(M, w2, c, wv, rowa, kg, acc2);
    }
  }

  // ---- epilogue: + b2 + win2 residual (global), NCHW scatter with unshift ----
  const int b  = wi >> 8;
  const int wh = (wi >> 4) & 15;
  const int ww = wi & 15;
  #pragma unroll
  for (int nt=0;nt<4;++nt){
    const int col = wv*64 + nt*16 + rowa;
    const float bias = b2[col];
    #pragma unroll
    for (int mt=0;mt<4;++mt){
      #pragma unroll
      for (int i=0;i<4;++i){
        const int row = mt*16 + kg*4 + i;
        float v = acc2[mt][nt][i] + bias + bf2f(win2[wbase + row*256 + col]);
        const int r = row >> 3, cw = row & 7;
        const int hh = (wh*8 + r + 4) & 127;
        const int wcc = (ww*8 + cw + 4) & 127;
        out[(((b<<8) + col) << 14) + hh*128 + wcc] = v;
      }
    }
  }
}

// ---------------- launch ----------------
extern "C" void kernel_launch(void* const* d_in, const int* in_sizes, int n_in,
                              void* d_out, int out_size, void* d_ws, size_t ws_size,
                              hipStream_t stream) {
  (void)in_sizes; (void)n_in; (void)out_size; (void)ws_size;
  const float* x    = (const float*)d_in[0];
  const float* ln1w = (const float*)d_in[1];
  const float* ln1b = (const float*)d_in[2];
  const float* inw  = (const float*)d_in[3];
  const float* inb  = (const float*)d_in[4];
  const float* outw = (const float*)d_in[5];
  const float* outb = (const float*)d_in[6];
  const float* ln2w = (const float*)d_in[7];
  const float* ln2b = (const float*)d_in[8];
  const float* w1f  = (const float*)d_in[9];
  const float* b1   = (const float*)d_in[10];
  const float* w2f  = (const float*)d_in[11];
  const float* b2   = (const float*)d_in[12];
  float* out = (float*)d_out;

  short* ws    = (short*)d_ws;
  short* wqkv  = ws;            // 768*256
  short* wout  = ws + 196608;   // 256*256
  short* w1b   = ws + 262144;   // 1024*256
  short* w2b   = ws + 524288;   // 256*1024
  short* win2  = ws + 786432;   // 2048*64*256 bf16

  hipLaunchKernelGGL(wconv_kernel, dim3(3072), dim3(256), 0, stream, inw, outw, w1f, w2f, ws);
  hipLaunchKernelGGL(swin_attn_kernel, dim3(2048), dim3(256), 0, stream,
                     x, ln1w, ln1b, inb, outb, wqkv, wout, win2);
  hipLaunchKernelGGL(swin_mlp_kernel, dim3(2048), dim3(256), 0, stream,
                     win2, ln2w, ln2b, b1, b2, w1b, w2b, out);
}

// Round 6
// 741.844 us; speedup vs baseline: 1.3159x; 1.0630x over previous
//
#include <hip/hip_runtime.h>
#include <math.h>

// Swin block: B=8, C=256, H=W=128, WS=8, SS=4, NH=8, dh=32
// 2048 windows x 64 tokens x 256 ch. All matmuls via mfma_f32_16x16x32_bf16.
// win2 is stored TRANSPOSED per window: win2T[wi][ch 256][tok 64] (bf16)

#define LDH 264   // bf16 row stride for [64][256] tiles
#define LDS_S 40  // bf16 row stride for per-wave [64][40] slots
#define LDM 136   // bf16 row stride for m chunk [64][128]

typedef __attribute__((ext_vector_type(8))) short bf16x8;
typedef __attribute__((ext_vector_type(4))) short bf16x4;
typedef __attribute__((ext_vector_type(4))) float f32x4;

static __device__ __forceinline__ float bf2f(short s){
  union { unsigned u; float f; } cv;
  cv.u = ((unsigned)(unsigned short)s) << 16;
  return cv.f;
}
static __device__ __forceinline__ short f2bf(float f){
  union { float f; unsigned u; } cv; cv.f = f;
  unsigned r = (cv.u + 0x7FFFu + ((cv.u >> 16) & 1u)) >> 16;  // RNE
  return (short)r;
}
static __device__ __forceinline__ float gelu_f(float x){
  return 0.5f * x * (1.0f + erff(x * 0.7071067811865475f));
}

// ---------------- K0: merged fp32 -> bf16 weight convert ----------------
__global__ void wconv_kernel(const float* __restrict__ inw, const float* __restrict__ outw,
                             const float* __restrict__ w1f, const float* __restrict__ w2f,
                             short* __restrict__ dst){
  int i = blockIdx.x * 256 + threadIdx.x;   // grid covers exactly 786432
  const float* s; int off;
  if (i < 196608){ s = inw;  off = 0; }
  else if (i < 262144){ s = outw; off = 196608; }
  else if (i < 524288){ s = w1f;  off = 262144; }
  else { s = w2f; off = 524288; }
  dst[i] = f2bf(s[i - off]);
}

// [64x256] @ [256 x 32] GEMM helper: A from sh_h, B rows wrowbase.. of w (bf16 [.][256])
__device__ __forceinline__ void gemm_h_w32(const short* __restrict__ sh_h,
                                           const short* __restrict__ w, int wrowbase,
                                           int rowa, int kg, f32x4 acc[4][2]){
  #pragma unroll
  for (int kt = 0; kt < 8; ++kt){
    bf16x8 av[4], bw[2];
    #pragma unroll
    for (int mt=0;mt<4;++mt)
      av[mt] = *(const bf16x8*)&sh_h[(mt*16+rowa)*LDH + kt*32 + kg*8];
    #pragma unroll
    for (int nt=0;nt<2;++nt)
      bw[nt] = *(const bf16x8*)&w[(wrowbase + nt*16 + rowa)*256 + kt*32 + kg*8];
    #pragma unroll
    for (int mt=0;mt<4;++mt)
      #pragma unroll
      for (int nt=0;nt<2;++nt)
        acc[mt][nt] = __builtin_amdgcn_mfma_f32_16x16x32_bf16(av[mt], bw[nt], acc[mt][nt], 0, 0, 0);
  }
}

// ---------------- kernel 1: LN1 + QKV + attention + out-proj(swapped) -> win2T ----------------
#define K1_OFF_WV  33792
#define K1_OFF_RED 74752
#define K1_SMEM    76800

__global__ __launch_bounds__(256, 2)
void swin_attn_kernel(const float* __restrict__ x,
                      const float* __restrict__ ln1w, const float* __restrict__ ln1b,
                      const float* __restrict__ inb,  const float* __restrict__ outb,
                      const short* __restrict__ wqkv, const short* __restrict__ wout,
                      short* __restrict__ win2T)
{
  __shared__ char smem[K1_SMEM];
  short* sh_h   = (short*)smem;
  float* red_s  = (float*)(smem + K1_OFF_RED);
  float* red_q2 = red_s + 256;

  const int tid = threadIdx.x;
  const int wv  = tid >> 6;
  const int ln  = tid & 63;
  const int rowa = ln & 15;
  const int kg   = ln >> 4;

  short* slotA = (short*)(smem + K1_OFF_WV) + wv*5120;  // [64][40]
  short* slotB = slotA + 2560;                          // [64][40]

  const int wi = blockIdx.x;
  const int b  = wi >> 8;
  const int wh = (wi >> 4) & 15;
  const int ww = wi & 15;

  const int hh = (wh*8 + (ln >> 3) + 4) & 127;   // roll(-4)
  const int wc = (ww*8 + (ln & 7) + 4) & 127;
  const int offhw = hh*128 + wc;
  const int xbase = b << 22;

  // ---- LN1 (values in regs) ----
  {
    const int cbeg = wv*64;
    float vals[64];
    float s = 0.f, sq = 0.f;
    #pragma unroll
    for (int j = 0; j < 64; ++j){
      float v = x[xbase + ((cbeg + j) << 14) + offhw];
      vals[j] = v; s += v; sq += v*v;
    }
    red_s[cbeg + ln]  = s;
    red_q2[cbeg + ln] = sq;
    __syncthreads();
    float sum = red_s[ln] + red_s[64+ln] + red_s[128+ln] + red_s[192+ln];
    float ssq = red_q2[ln] + red_q2[64+ln] + red_q2[128+ln] + red_q2[192+ln];
    float mean = sum * 0.00390625f;
    float var  = ssq * 0.00390625f - mean*mean;
    float rstd = rsqrtf(var + 1e-5f);
    #pragma unroll
    for (int j = 0; j < 64; ++j){
      const int c = cbeg + j;
      sh_h[ln*LDH + c] = f2bf((vals[j] - mean) * rstd * ln1w[c] + ln1b[c]);
    }
  }
  __syncthreads();

  // ---- per-wave, per-head attention; wave wv owns heads 2wv, 2wv+1 ----
  const float scale = 0.1767766952966369f;  // 1/sqrt(32)
  f32x4 oacc[4][4];
  #pragma unroll
  for (int mt=0;mt<4;++mt)
    #pragma unroll
    for (int j=0;j<4;++j)
      oacc[mt][j] = (f32x4){0.f,0.f,0.f,0.f};

  #pragma unroll
  for (int hd = 0; hd < 2; ++hd){
    const int hc = (2*wv + hd) * 32;

    // q -> slotA
    {
      f32x4 accq[4][2];
      #pragma unroll
      for (int mt=0;mt<4;++mt){ accq[mt][0]=(f32x4){0,0,0,0}; accq[mt][1]=(f32x4){0,0,0,0}; }
      gemm_h_w32(sh_h, wqkv, 0*256 + hc, rowa, kg, accq);
      #pragma unroll
      for (int nt=0;nt<2;++nt){
        const float bias = inb[hc + nt*16 + rowa];
        #pragma unroll
        for (int mt=0;mt<4;++mt)
          #pragma unroll
          for (int i=0;i<4;++i)
            slotA[(mt*16 + kg*4 + i)*LDS_S + nt*16 + rowa] = f2bf(accq[mt][nt][i] + bias);
      }
    }
    // k -> slotB
    {
      f32x4 acck[4][2];
      #pragma unroll
      for (int mt=0;mt<4;++mt){ acck[mt][0]=(f32x4){0,0,0,0}; acck[mt][1]=(f32x4){0,0,0,0}; }
      gemm_h_w32(sh_h, wqkv, 1*256 + hc, rowa, kg, acck);
      #pragma unroll
      for (int nt=0;nt<2;++nt){
        const float bias = inb[256 + hc + nt*16 + rowa];
        #pragma unroll
        for (int mt=0;mt<4;++mt)
          #pragma unroll
          for (int i=0;i<4;++i)
            slotB[(mt*16 + kg*4 + i)*LDS_S + nt*16 + rowa] = f2bf(acck[mt][nt][i] + bias);
      }
    }

    // S = q @ k^T
    f32x4 sacc[4][4];
    #pragma unroll
    for (int mt=0;mt<4;++mt)
      #pragma unroll
      for (int nt=0;nt<4;++nt)
        sacc[mt][nt] = (f32x4){0.f,0.f,0.f,0.f};
    {
      bf16x8 aq[4], bk[4];
      #pragma unroll
      for (int mt=0;mt<4;++mt)
        aq[mt] = *(const bf16x8*)&slotA[(mt*16+rowa)*LDS_S + kg*8];
      #pragma unroll
      for (int nt=0;nt<4;++nt)
        bk[nt] = *(const bf16x8*)&slotB[(nt*16+rowa)*LDS_S + kg*8];
      __builtin_amdgcn_s_setprio(1);
      #pragma unroll
      for (int mt=0;mt<4;++mt)
        #pragma unroll
        for (int nt=0;nt<4;++nt)
          sacc[mt][nt] = __builtin_amdgcn_mfma_f32_16x16x32_bf16(aq[mt], bk[nt], sacc[mt][nt], 0, 0, 0);
      __builtin_amdgcn_s_setprio(0);
    }

    // v -> vT in slotB
    {
      f32x4 accv[4][2];
      #pragma unroll
      for (int mt=0;mt<4;++mt){ accv[mt][0]=(f32x4){0,0,0,0}; accv[mt][1]=(f32x4){0,0,0,0}; }
      gemm_h_w32(sh_h, wqkv, 2*256 + hc, rowa, kg, accv);
      #pragma unroll
      for (int nt=0;nt<2;++nt){
        const float bias = inb[512 + hc + nt*16 + rowa];
        #pragma unroll
        for (int mt=0;mt<4;++mt)
          #pragma unroll
          for (int i=0;i<4;++i)
            slotB[(nt*16 + rowa)*LDS_S + mt*16 + kg*4 + i] = f2bf(accv[mt][nt][i] + bias);  // [ch][tok]
      }
    }

    // softmax
    #pragma unroll
    for (int mt=0;mt<4;++mt){
      #pragma unroll
      for (int i=0;i<4;++i){
        float v0 = sacc[mt][0][i]*scale;
        float v1 = sacc[mt][1][i]*scale;
        float v2 = sacc[mt][2][i]*scale;
        float v3 = sacc[mt][3][i]*scale;
        float mx = fmaxf(fmaxf(v0,v1), fmaxf(v2,v3));
        #pragma unroll
        for (int d=1; d<16; d<<=1) mx = fmaxf(mx, __shfl_xor(mx, d, 64));
        v0 = __expf(v0-mx); v1 = __expf(v1-mx); v2 = __expf(v2-mx); v3 = __expf(v3-mx);
        float sm = v0+v1+v2+v3;
        #pragma unroll
        for (int d=1; d<16; d<<=1) sm += __shfl_xor(sm, d, 64);
        const float inv = 1.f / sm;
        sacc[mt][0][i] = v0*inv; sacc[mt][1][i] = v1*inv;
        sacc[mt][2][i] = v2*inv; sacc[mt][3][i] = v3*inv;
      }
    }

    // PV in two kv-chunks of 32, P through slotA
    #pragma unroll
    for (int ck=0; ck<2; ++ck){
      #pragma unroll
      for (int ntl=0; ntl<2; ++ntl)
        #pragma unroll
        for (int mt=0;mt<4;++mt)
          #pragma unroll
          for (int i=0;i<4;++i)
            slotA[(mt*16 + kg*4 + i)*LDS_S + ntl*16 + rowa] = f2bf(sacc[mt][2*ck+ntl][i]);
      bf16x8 ap[4], bv[2];
      #pragma unroll
      for (int mt=0;mt<4;++mt)
        ap[mt] = *(const bf16x8*)&slotA[(mt*16+rowa)*LDS_S + kg*8];
      #pragma unroll
      for (int nt=0;nt<2;++nt)
        bv[nt] = *(const bf16x8*)&slotB[(nt*16+rowa)*LDS_S + kg*8];
      __builtin_amdgcn_s_setprio(1);
      #pragma unroll
      for (int mt=0;mt<4;++mt)
        #pragma unroll
        for (int nt=0;nt<2;++nt)
          oacc[mt][hd*2+nt] = __builtin_amdgcn_mfma_f32_16x16x32_bf16(ap[mt], bv[nt], oacc[mt][hd*2+nt], 0, 0, 0);
      __builtin_amdgcn_s_setprio(0);
    }
  }

  __syncthreads();   // all waves done with h -> region becomes o

  #pragma unroll
  for (int j=0;j<4;++j){
    const int col = wv*64 + j*16 + rowa;
    #pragma unroll
    for (int mt=0;mt<4;++mt)
      #pragma unroll
      for (int i=0;i<4;++i)
        sh_h[(mt*16 + kg*4 + i)*LDH + col] = f2bf(oacc[mt][j][i]);
  }
  __syncthreads();

  // ---- out-proj SWAPPED: D'[ch][tok] = wout x o^T; + bias + x residual -> win2T ----
  // A-frag = wout rows (ch), B-frag = o tokens (identical LDS reads as before).
  {
    f32x4 acc[4][4];   // [cht(ch)][tt(tok)]
    #pragma unroll
    for (int c0=0;c0<4;++c0)
      #pragma unroll
      for (int t0=0;t0<4;++t0)
        acc[c0][t0] = (f32x4){0.f,0.f,0.f,0.f};
    for (int kt=0; kt<8; ++kt){
      bf16x8 aw[4], bo[4];
      #pragma unroll
      for (int c0=0;c0<4;++c0)
        aw[c0] = *(const bf16x8*)&wout[(wv*64 + c0*16 + rowa)*256 + kt*32 + kg*8];
      #pragma unroll
      for (int t0=0;t0<4;++t0)
        bo[t0] = *(const bf16x8*)&sh_h[(t0*16+rowa)*LDH + kt*32 + kg*8];
      #pragma unroll
      for (int c0=0;c0<4;++c0)
        #pragma unroll
        for (int t0=0;t0<4;++t0)
          acc[c0][t0] = __builtin_amdgcn_mfma_f32_16x16x32_bf16(aw[c0], bo[t0], acc[c0][t0], 0, 0, 0);
    }
    // D' rows = ch = wv*64 + c0*16 + kg*4 + i ; cols = tok = t0*16 + rowa
    #pragma unroll
    for (int c0=0;c0<4;++c0){
      #pragma unroll
      for (int i=0;i<4;++i){
        const int ch = wv*64 + c0*16 + kg*4 + i;
        const float bias = outb[ch];
        #pragma unroll
        for (int t0=0;t0<4;++t0){
          const int tok = t0*16 + rowa;
          const int r = tok >> 3, cw = tok & 7;
          const int hh2 = (wh*8 + r + 4) & 127;
          const int wc2 = (ww*8 + cw + 4) & 127;
          const float res = x[xbase + (ch << 14) + hh2*128 + wc2];   // coalesced over rowa
          win2T[(wi<<14) + ch*64 + tok] = f2bf(acc[c0][t0][i] + bias + res);
        }
      }
    }
  }
}

// ---------------- kernel 2: LN2 + pipelined MLP (GEMM2 swapped) + residual + scatter ----------------
// LDS (53248 B -> 3 blocks/CU):
//   [0,     33792)  Y: h2 bf16 [64][264]
//   [33792, 51200)  M: m chunk bf16 [64][136] (128 hidden)
//   [51200, 53248)  reduce scratch 2x[256] f32
#define K2_OFF_M   33792
#define K2_OFF_RED 51200
#define K2_SMEM    53248

// GEMM1(chunk): acc1[rt][ct] += w1-rows x Y-tokens (operand-swapped, D[hid][tok])
__device__ __forceinline__ void mlp_gemm1(const short* __restrict__ w1, const short* Y,
                                          int chk, int wv, int rowa, int kg,
                                          f32x4 acc1[2][4]){
  #pragma unroll
  for (int kt=0;kt<8;++kt){
    bf16x8 aw[2], bh[4];
    #pragma unroll
    for (int rt=0;rt<2;++rt)
      aw[rt] = *(const bf16x8*)&w1[(chk*128 + wv*32 + rt*16 + rowa)*256 + kt*32 + kg*8];
    #pragma unroll
    for (int ct=0;ct<4;++ct)
      bh[ct] = *(const bf16x8*)&Y[(ct*16+rowa)*LDH + kt*32 + kg*8];
    #pragma unroll
    for (int rt=0;rt<2;++rt)
      #pragma unroll
      for (int ct=0;ct<4;++ct)
        acc1[rt][ct] = __builtin_amdgcn_mfma_f32_16x16x32_bf16(aw[rt], bh[ct], acc1[rt][ct], 0, 0, 0);
  }
}

// GELU(acc1)+bias -> M (b64-packed writes)
__device__ __forceinline__ void mlp_gelu_store(short* M, const float* __restrict__ b1,
                                               int chk, int wv, int rowa, int kg,
                                               const f32x4 acc1[2][4]){
  #pragma unroll
  for (int rt=0;rt<2;++rt){
    const int hidb = wv*32 + rt*16 + kg*4;       // hid within chunk
    const f32x4 b1v = *(const f32x4*)&b1[chk*128 + hidb];
    #pragma unroll
    for (int ct=0;ct<4;++ct){
      bf16x4 st;
      #pragma unroll
      for (int i=0;i<4;++i)
        st[i] = f2bf(gelu_f(acc1[rt][ct][i] + b1v[i]));
      *(bf16x4*)&M[(ct*16 + rowa)*LDM + hidb] = st;
    }
  }
}

// GEMM2(chunk) SWAPPED: acc2[cht][tt] += w2-ch-rows x M-tokens (same loads as unswapped)
__device__ __forceinline__ void mlp_gemm2(const short* M, const short* __restrict__ w2,
                                          int chk, int wv, int rowa, int kg,
                                          f32x4 acc2[4][4]){
  #pragma unroll
  for (int kt2=0;kt2<4;++kt2){
    bf16x8 aw2[4], bm[4];
    #pragma unroll
    for (int c0=0;c0<4;++c0)
      aw2[c0] = *(const bf16x8*)&w2[(wv*64 + c0*16+rowa)*1024 + chk*128 + kt2*32 + kg*8];
    #pragma unroll
    for (int t0=0;t0<4;++t0)
      bm[t0] = *(const bf16x8*)&M[(t0*16+rowa)*LDM + kt2*32 + kg*8];
    #pragma unroll
    for (int c0=0;c0<4;++c0)
      #pragma unroll
      for (int t0=0;t0<4;++t0)
        acc2[c0][t0] = __builtin_amdgcn_mfma_f32_16x16x32_bf16(aw2[c0], bm[t0], acc2[c0][t0], 0, 0, 0);
  }
}

__global__ __launch_bounds__(256, 3)
void swin_mlp_kernel(const short* __restrict__ win2T,
                     const float* __restrict__ ln2w, const float* __restrict__ ln2b,
                     const float* __restrict__ b1,   const float* __restrict__ b2,
                     const short* __restrict__ w1,   const short* __restrict__ w2,
                     float* __restrict__ out)
{
  __shared__ char smem[K2_SMEM];
  short* Y = (short*)smem;
  short* M = (short*)(smem + K2_OFF_M);
  float* red_s  = (float*)(smem + K2_OFF_RED);
  float* red_q2 = red_s + 256;

  const int tid = threadIdx.x;
  const int wv  = tid >> 6;
  const int ln  = tid & 63;
  const int rowa = ln & 15;
  const int kg   = ln >> 4;
  const int wi = blockIdx.x;
  const int wb = wi << 14;   // win2T window base (256*64)

  // ---- LN2 from win2T (row-major over ch => coalesced 128B lines per wave) ----
  {
    float vals[64];
    float s = 0.f, sq = 0.f;
    const int cbeg = wv*64;
    #pragma unroll
    for (int j=0;j<64;++j){
      float v = bf2f(win2T[wb + (cbeg + j)*64 + ln]);
      vals[j] = v; s += v; sq += v*v;
    }
    red_s[cbeg + ln]  = s;
    red_q2[cbeg + ln] = sq;
    __syncthreads();
    float sum = red_s[ln] + red_s[64+ln] + red_s[128+ln] + red_s[192+ln];
    float ssq = red_q2[ln] + red_q2[64+ln] + red_q2[128+ln] + red_q2[192+ln];
    float mean = sum * 0.00390625f;
    float var  = ssq * 0.00390625f - mean*mean;
    float rstd = rsqrtf(var + 1e-5f);
    #pragma unroll
    for (int q=0;q<8;++q){
      bf16x8 pk;
      #pragma unroll
      for (int e=0;e<8;++e){
        const int c = cbeg + q*8 + e;
        pk[e] = f2bf((vals[q*8+e] - mean) * rstd * ln2w[c] + ln2b[c]);
      }
      *(bf16x8*)&Y[ln*LDH + cbeg + q*8] = pk;
    }
  }
  __syncthreads();

  // ---- pipelined MLP: GEMM1(c+1) overlaps GEMM2(c) ----
  f32x4 acc2[4][4];
  #pragma unroll
  for (int c0=0;c0<4;++c0)
    #pragma unroll
    for (int t0=0;t0<4;++t0)
      acc2[c0][t0] = (f32x4){0.f,0.f,0.f,0.f};

  // prologue: chunk 0 -> M
  {
    f32x4 acc1[2][4];
    #pragma unroll
    for (int rt=0;rt<2;++rt)
      #pragma unroll
      for (int ct=0;ct<4;++ct)
        acc1[rt][ct] = (f32x4){0.f,0.f,0.f,0.f};
    mlp_gemm1(w1, Y, 0, wv, rowa, kg, acc1);
    mlp_gelu_store(M, b1, 0, wv, rowa, kg, acc1);
  }
  __syncthreads();   // M(0) ready

  #pragma unroll
  for (int c = 0; c < 8; ++c){
    if (c < 7){
      f32x4 acc1n[2][4];
      #pragma unroll
      for (int rt=0;rt<2;++rt)
        #pragma unroll
        for (int ct=0;ct<4;++ct)
          acc1n[rt][ct] = (f32x4){0.f,0.f,0.f,0.f};
      mlp_gemm1(w1, Y, c+1, wv, rowa, kg, acc1n);
      mlp_gemm2(M, w2, c, wv, rowa, kg, acc2);
      __syncthreads();   // all M(c) reads done
      mlp_gelu_store(M, b1, c+1, wv, rowa, kg, acc1n);
      __syncthreads();   // M(c+1) ready
    } else {
      mlp_gemm2(M, w2, c, wv, rowa, kg, acc2);
    }
  }

  // ---- epilogue: D'[ch][tok]: + b2 + win2T residual (coalesced), coalesced NCHW store ----
  const int b  = wi >> 8;
  const int wh = (wi >> 4) & 15;
  const int ww = wi & 15;
  #pragma unroll
  for (int c0=0;c0<4;++c0){
    #pragma unroll
    for (int i=0;i<4;++i){
      const int ch = wv*64 + c0*16 + kg*4 + i;
      const float bias = b2[ch];
      #pragma unroll
      for (int t0=0;t0<4;++t0){
        const int tok = t0*16 + rowa;
        float v = acc2[c0][t0][i] + bias + bf2f(win2T[wb + ch*64 + tok]);
        const int r = tok >> 3, cw = tok & 7;
        const int hh = (wh*8 + r + 4) & 127;
        const int wcc = (ww*8 + cw + 4) & 127;
        out[(((b<<8) + ch) << 14) + hh*128 + wcc] = v;
      }
    }
  }
}

// ---------------- launch ----------------
extern "C" void kernel_launch(void* const* d_in, const int* in_sizes, int n_in,
                              void* d_out, int out_size, void* d_ws, size_t ws_size,
                              hipStream_t stream) {
  (void)in_sizes; (void)n_in; (void)out_size; (void)ws_size;
  const float* x    = (const float*)d_in[0];
  const float* ln1w = (const float*)d_in[1];
  const float* ln1b = (const float*)d_in[2];
  const float* inw  = (const float*)d_in[3];
  const float* inb  = (const float*)d_in[4];
  const float* outw = (const float*)d_in[5];
  const float* outb = (const float*)d_in[6];
  const float* ln2w = (const float*)d_in[7];
  const float* ln2b = (const float*)d_in[8];
  const float* w1f  = (const float*)d_in[9];
  const float* b1   = (const float*)d_in[10];
  const float* w2f  = (const float*)d_in[11];
  const float* b2   = (const float*)d_in[12];
  float* out = (float*)d_out;

  short* ws    = (short*)d_ws;
  short* wqkv  = ws;            // 768*256
  short* wout  = ws + 196608;   // 256*256
  short* w1b   = ws + 262144;   // 1024*256
  short* w2b   = ws + 524288;   // 256*1024
  short* win2T = ws + 786432;   // 2048 windows x 256 ch x 64 tok bf16 (transposed)

  hipLaunchKernelGGL(wconv_kernel, dim3(3072), dim3(256), 0, stream, inw, outw, w1f, w2f, ws);
  hipLaunchKernelGGL(swin_attn_kernel, dim3(2048), dim3(256), 0, stream,
                     x, ln1w, ln1b, inb, outb, wqkv, wout, win2T);
  hipLaunchKernelGGL(swin_mlp_kernel, dim3(2048), dim3(256), 0, stream,
                     win2T, ln2w, ln2b, b1, b2, w1b, w2b, out);
}